// Round 7
// baseline (7008.185 us; speedup 1.0000x reference)
//
#include <hip/hip_runtime.h>
#include <stdint.h>

// LSTM forward, B=32 T=2048 D=512 H=512 G=2048.
// Round 7: latency-hiding via chain interleaving. Each WG owns TWO
// independent batch-group chains (A=pr*2, B=pr*2+1) over 32 h-cols (nw).
// Slices alternate A/B; chain r's tagged polls are issued at the end of its
// slice and checked one slice later -> handoff RTT hidden behind the other
// chain's compute. All loop VMEM is inline asm, fixed 9-op FIFO per slice
// [pub][out x3][gx][polls x4]; steady-state check = counted vmcnt(9).
// Exchange protocol unchanged: tagged dwords (lo16 bf16 h | hi16 step),
// double-buffered slots, all traffic sc0 sc1 (MALL-coherent).

#define B_ 32
#define T_ 2048
#define D_ 512
#define H_ 512
#define G_ 2048
#define NCG 16
#define NBG 8

typedef __attribute__((ext_vector_type(4))) float f32x4;
typedef __attribute__((ext_vector_type(8))) short bf16x8;
typedef __attribute__((ext_vector_type(4))) unsigned int uint4v;
typedef __attribute__((ext_vector_type(2))) unsigned int uint2v;

__device__ __forceinline__ unsigned short f2bf(float f) {
  union { float f; unsigned int u; } v; v.f = f;
  unsigned int r = (v.u + 0x7FFFu + ((v.u >> 16) & 1u)) >> 16;
  return (unsigned short)r;
}
__device__ __forceinline__ float bf2f(unsigned short s) {
  union { unsigned int u; float f; } v; v.u = ((unsigned int)s) << 16;
  return v.f;
}
__device__ __forceinline__ float sigm(float x) { return 1.0f / (1.0f + __expf(-x)); }
__device__ __forceinline__ float tanh_(float x) { return 1.0f - 2.0f / (__expf(2.0f * x) + 1.0f); }

__device__ __forceinline__ void store_x4_coherent(unsigned int* p, uint4v v) {
  asm volatile("global_store_dwordx4 %0, %1, off sc0 sc1" :: "v"(p), "v"(v) : "memory");
}

#define BARRIER_LGKM()                                          \
  do {                                                          \
    asm volatile("s_waitcnt lgkmcnt(0)" ::: "memory");          \
    __builtin_amdgcn_sched_barrier(0);                          \
    __builtin_amdgcn_s_barrier();                               \
    __builtin_amdgcn_sched_barrier(0);                          \
  } while (0)

#define VMWAIT(N)                                               \
  do { asm volatile("s_waitcnt vmcnt(" #N ")" ::: "memory");    \
       __builtin_amdgcn_sched_barrier(0); } while (0)

// ---------------- Phase 1: convert inputs + seed/clear h_tag ----------------
__global__ __launch_bounds__(256) void prep_kernel(
    const float* __restrict__ x, const float* __restrict__ w_ih,
    const float* __restrict__ hx,
    unsigned short* __restrict__ x_bf, unsigned short* __restrict__ w_bf,
    unsigned int* __restrict__ h_tag) {
  const int NX8 = (B_ * T_ * D_) / 8;   // 4,194,304
  const int NWT8 = (G_ * D_) / 8;       // 131,072
  int i = blockIdx.x * 256 + threadIdx.x;
  if (i < NX8) {
    float4 a = reinterpret_cast<const float4*>(x)[i * 2];
    float4 b = reinterpret_cast<const float4*>(x)[i * 2 + 1];
    uint4v v;
    v[0] = (unsigned)f2bf(a.x) | ((unsigned)f2bf(a.y) << 16);
    v[1] = (unsigned)f2bf(a.z) | ((unsigned)f2bf(a.w) << 16);
    v[2] = (unsigned)f2bf(b.x) | ((unsigned)f2bf(b.y) << 16);
    v[3] = (unsigned)f2bf(b.z) | ((unsigned)f2bf(b.w) << 16);
    reinterpret_cast<uint4v*>(x_bf)[i] = v;
  } else if (i < NX8 + NWT8) {
    int j = i - NX8;
    float4 a = reinterpret_cast<const float4*>(w_ih)[j * 2];
    float4 b = reinterpret_cast<const float4*>(w_ih)[j * 2 + 1];
    uint4v v;
    v[0] = (unsigned)f2bf(a.x) | ((unsigned)f2bf(a.y) << 16);
    v[1] = (unsigned)f2bf(a.z) | ((unsigned)f2bf(a.w) << 16);
    v[2] = (unsigned)f2bf(b.x) | ((unsigned)f2bf(b.y) << 16);
    v[3] = (unsigned)f2bf(b.z) | ((unsigned)f2bf(b.w) << 16);
    reinterpret_cast<uint4v*>(w_bf)[j] = v;
  } else if (i < NX8 + NWT8 + 2048) {
    int j = i - NX8 - NWT8;  // seed slot 0 from hx, tag 0
    float4 a = reinterpret_cast<const float4*>(hx)[j * 2];
    float4 b = reinterpret_cast<const float4*>(hx)[j * 2 + 1];
    uint4v v0, v1;
    v0[0] = f2bf(a.x); v0[1] = f2bf(a.y); v0[2] = f2bf(a.z); v0[3] = f2bf(a.w);
    v1[0] = f2bf(b.x); v1[1] = f2bf(b.y); v1[2] = f2bf(b.z); v1[3] = f2bf(b.w);
    unsigned int* p = h_tag + j * 8;
    store_x4_coherent(p, v0);
    store_x4_coherent(p + 4, v1);
  } else {
    int j = i - NX8 - NWT8 - 2048;  // clear slot 1
    unsigned int* p = h_tag + 16384 + j * 8;
    uint4v z = {0u, 0u, 0u, 0u};
    store_x4_coherent(p, z);
    store_x4_coherent(p + 4, z);
  }
}

// ---------------- Phase 2: gx GEMM (unchanged) ----------------
__global__ __launch_bounds__(256, 2) void gemm_gx(
    const unsigned short* __restrict__ x_bf, const unsigned short* __restrict__ w_bf,
    const float* __restrict__ b_ih, const float* __restrict__ b_hh,
    unsigned short* __restrict__ gx_ws) {
  __shared__ unsigned short As[128 * 40];
  __shared__ unsigned short Bs[128 * 40];
  __shared__ unsigned short Eg[128 * 136];
  const int bid = blockIdx.x;
  const int cb = bid & 15, rb = bid >> 4;
  const int r0 = rb * 128, c0 = cb * 128;
  const int tid = threadIdx.x;
  const int lane = tid & 63;
  const int w = tid >> 6;
  const int qr = (w >> 1) * 64, qc = (w & 1) * 64;
  f32x4 acc[4][4] = {};

  for (int kt = 0; kt < 16; ++kt) {
    const int k0 = kt * 32;
    uint4v av[2], bv[2];
#pragma unroll
    for (int c = 0; c < 2; ++c) {
      int flat = c * 256 + tid;
      int row = flat >> 2, q = flat & 3;
      av[c] = *reinterpret_cast<const uint4v*>(x_bf + (size_t)(r0 + row) * 512 + k0 + q * 8);
      bv[c] = *reinterpret_cast<const uint4v*>(w_bf + (size_t)(c0 + row) * 512 + k0 + q * 8);
    }
    __syncthreads();
#pragma unroll
    for (int c = 0; c < 2; ++c) {
      int flat = c * 256 + tid;
      int row = flat >> 2, q = flat & 3;
      *reinterpret_cast<uint4v*>(&As[row * 40 + q * 8]) = av[c];
      *reinterpret_cast<uint4v*>(&Bs[row * 40 + q * 8]) = bv[c];
    }
    __syncthreads();
    bf16x8 af[4], bfr[4];
#pragma unroll
    for (int mt = 0; mt < 4; ++mt)
      af[mt] = *reinterpret_cast<const bf16x8*>(&As[(qr + mt * 16 + (lane & 15)) * 40 + (lane >> 4) * 8]);
#pragma unroll
    for (int nt = 0; nt < 4; ++nt)
      bfr[nt] = *reinterpret_cast<const bf16x8*>(&Bs[(qc + nt * 16 + (lane & 15)) * 40 + (lane >> 4) * 8]);
#pragma unroll
    for (int mt = 0; mt < 4; ++mt)
#pragma unroll
      for (int nt = 0; nt < 4; ++nt)
        acc[mt][nt] = __builtin_amdgcn_mfma_f32_16x16x32_bf16(af[mt], bfr[nt], acc[mt][nt], 0, 0, 0);
  }
  __syncthreads();
#pragma unroll
  for (int nt = 0; nt < 4; ++nt) {
    int cg = c0 + qc + nt * 16 + (lane & 15);
    float bias = b_ih[cg] + b_hh[cg];
#pragma unroll
    for (int mt = 0; mt < 4; ++mt)
#pragma unroll
      for (int j = 0; j < 4; ++j) {
        int tr = qr + mt * 16 + (lane >> 4) * 4 + j;
        int cl = qc + nt * 16 + (lane & 15);
        Eg[tr * 136 + cl] = f2bf(acc[mt][nt][j] + bias);
      }
  }
  __syncthreads();
  const int b = r0 >> 11;
  const int g = c0 >> 9;
  const int t0 = r0 & 2047;
  const int nw0 = (c0 & 511) >> 5;
  const int bg = b >> 2, bq = b & 3;
  for (int c = tid; c < 512; c += 256) {
    int tr = c >> 2, nwi = c & 3;
    size_t dst = (((size_t)(t0 + tr) * NBG + bg) * NCG + (nw0 + nwi)) * 512 + bq * 128 + g * 32;
    const unsigned short* src = &Eg[tr * 136 + nwi * 32];
#pragma unroll
    for (int q = 0; q < 4; ++q)
      *reinterpret_cast<uint4v*>(gx_ws + dst + q * 8) =
          *reinterpret_cast<const uint4v*>(src + q * 8);
  }
}

// ---------------- Phase 3: recurrence (2 chains / WG) ----------------
#define POLLS(H0, H1, H2, H3, PB)                                                           \
  do {                                                                                      \
    const unsigned int* pb_ = (PB);                                                         \
    const unsigned int* pb2_ = pb_ + 1024;                                                  \
    asm volatile("global_load_dwordx4 %0, %1, off sc0 sc1" : "=v"(H0) : "v"(pb_));          \
    asm volatile("global_load_dwordx4 %0, %1, off offset:2048 sc0 sc1" : "=v"(H1) : "v"(pb_)); \
    asm volatile("global_load_dwordx4 %0, %1, off sc0 sc1" : "=v"(H2) : "v"(pb2_));         \
    asm volatile("global_load_dwordx4 %0, %1, off offset:2048 sc0 sc1" : "=v"(H3) : "v"(pb2_)); \
  } while (0)

#define CHK16(H0, H1, H2, H3, W)                                                  \
  (((H0[0] >> 16) ^ (W)) | ((H0[1] >> 16) ^ (W)) | ((H0[2] >> 16) ^ (W)) |        \
   ((H0[3] >> 16) ^ (W)) | ((H1[0] >> 16) ^ (W)) | ((H1[1] >> 16) ^ (W)) |        \
   ((H1[2] >> 16) ^ (W)) | ((H1[3] >> 16) ^ (W)) | ((H2[0] >> 16) ^ (W)) |        \
   ((H2[1] >> 16) ^ (W)) | ((H2[2] >> 16) ^ (W)) | ((H2[3] >> 16) ^ (W)) |        \
   ((H3[0] >> 16) ^ (W)) | ((H3[1] >> 16) ^ (W)) | ((H3[2] >> 16) ^ (W)) |        \
   ((H3[3] >> 16) ^ (W)))

#define SPIN(H0, H1, H2, H3, PB, W)                                               \
  do {                                                                            \
    unsigned bad_ = CHK16(H0, H1, H2, H3, (W));                                   \
    int guard_ = 0;                                                               \
    while (bad_) {                                                                \
      POLLS(H0, H1, H2, H3, (PB));                                                \
      VMWAIT(0);                                                                  \
      bad_ = CHK16(H0, H1, H2, H3, (W));                                          \
      if (++guard_ > (1 << 20)) break;                                            \
    }                                                                             \
  } while (0)

#define UNPACK(H0, H1, H2, H3, GXV)                                               \
  do {                                                                            \
    uint2v pk_;                                                                   \
    pk_[0] = (H0[0] & 0xffffu) | (H0[1] << 16);                                   \
    pk_[1] = (H0[2] & 0xffffu) | (H0[3] << 16);                                   \
    *reinterpret_cast<uint2v*>(&As[0 * 536 + tid * 4]) = pk_;                     \
    pk_[0] = (H1[0] & 0xffffu) | (H1[1] << 16);                                   \
    pk_[1] = (H1[2] & 0xffffu) | (H1[3] << 16);                                   \
    *reinterpret_cast<uint2v*>(&As[1 * 536 + tid * 4]) = pk_;                     \
    pk_[0] = (H2[0] & 0xffffu) | (H2[1] << 16);                                   \
    pk_[1] = (H2[2] & 0xffffu) | (H2[3] << 16);                                   \
    *reinterpret_cast<uint2v*>(&As[2 * 536 + tid * 4]) = pk_;                     \
    pk_[0] = (H3[0] & 0xffffu) | (H3[1] << 16);                                   \
    pk_[1] = (H3[2] & 0xffffu) | (H3[3] << 16);                                   \
    *reinterpret_cast<uint2v*>(&As[3 * 536 + tid * 4]) = pk_;                     \
    *reinterpret_cast<uint2v*>(&GxL[tid * 4]) = (GXV);                            \
  } while (0)

#define MFMA_BLOCK()                                                              \
  do {                                                                            \
    f32x4 a0_ = {}, a1_ = {};                                                     \
    _Pragma("unroll")                                                             \
    for (int kk = 0; kk < 16; kk += 2) {                                          \
      bf16x8 af0_ = *reinterpret_cast<const bf16x8*>(                             \
          &As[(lane & 3) * 536 + kk * 32 + (lane >> 4) * 8]);                     \
      bf16x8 af1_ = *reinterpret_cast<const bf16x8*>(                             \
          &As[(lane & 3) * 536 + (kk + 1) * 32 + (lane >> 4) * 8]);               \
      a0_ = __builtin_amdgcn_mfma_f32_16x16x32_bf16(af0_, breg[kk], a0_, 0, 0, 0);\
      a1_ = __builtin_amdgcn_mfma_f32_16x16x32_bf16(af1_, breg[kk + 1], a1_, 0, 0, 0); \
    }                                                                             \
    if (lane < 16)                                                                \
      *reinterpret_cast<f32x4*>(&Gt2[w * 64 + lane * 4]) = a0_ + a1_;             \
  } while (0)

// elem: FIFO = pub(1), out(3), gx(1), polls(4) = 9 ops per slice.
#define ELEM(CVAR, BNO, Q0, Q1, OF, OH, OG, GBASE, GXV, P0, P1, H0, H1, H2, H3)   \
  do {                                                                            \
    float s0_ = Gt2[(0 + w) * 64 + lane] + bf2f(GxL[bq * 128 + 0 + jl]);          \
    float s1_ = Gt2[(2 + w) * 64 + lane] + bf2f(GxL[bq * 128 + 32 + jl]);         \
    float s2_ = Gt2[(4 + w) * 64 + lane] + bf2f(GxL[bq * 128 + 64 + jl]);         \
    float s3_ = Gt2[(6 + w) * 64 + lane] + bf2f(GxL[bq * 128 + 96 + jl]);         \
    float ia_ = sigm(s0_), fa_ = sigm(s1_), ga_ = tanh_(s2_), oa_ = sigm(s3_);    \
    CVAR = fa_ * CVAR + ia_ * ga_;                                                \
    float h_ = oa_ * tanh_(CVAR);                                                 \
    unsigned word_ = (unsigned)f2bf(h_) | (((unsigned)(t + 1)) << 16);            \
    unsigned int* q_ = ((t + 1) & 1) ? (Q1) : (Q0);                               \
    asm volatile("global_store_dword %0, %1, off sc0 sc1" :: "v"(q_), "v"(word_) : "memory"); \
    const float* pf_ = (OF) + (size_t)t * H_;                                     \
    asm volatile("global_store_dword %0, %1, off" :: "v"(pf_), "v"(fa_) : "memory"); \
    const float* ph_ = (OH) + (size_t)t * H_;                                     \
    asm volatile("global_store_dword %0, %1, off" :: "v"(ph_), "v"(h_) : "memory");  \
    const float* pg_ = (OG) + (size_t)t * H_;                                     \
    asm volatile("global_store_dword %0, %1, off" :: "v"(pg_), "v"(ga_) : "memory"); \
    const unsigned short* gp_ = (GBASE) + (size_t)(t + 1) * 65536;                \
    asm volatile("global_load_dwordx2 %0, %1, off" : "=v"(GXV) : "v"(gp_));       \
    const unsigned int* pb_ = ((t + 1) & 1) ? (P1) : (P0);                        \
    POLLS(H0, H1, H2, H3, pb_);                                                   \
    if (t == T_ - 1) {                                                            \
      float* po_ = out + (size_t)3 * B_ * T_ * H_ + (size_t)(BNO) * H_ + col;     \
      asm volatile("global_store_dword %0, %1, off" :: "v"(po_), "v"(oa_) : "memory"); \
    }                                                                             \
  } while (0)

__global__ __launch_bounds__(512) void lstm_rec(
    const float* __restrict__ cx, const float* __restrict__ w_hh,
    const unsigned short* __restrict__ gx_ws, unsigned int* __restrict__ h_tag,
    float* __restrict__ out) {
  const int bid = blockIdx.x;
  const int nw = bid & 15;        // col-group: h-cols [nw*32, +32)
  const int pr = bid >> 4;        // bg pair
  const int bgA = pr * 2, bgB = pr * 2 + 1;
  const int tid = threadIdx.x;
  const int lane = tid & 63;
  const int w = tid >> 6;
  const int gi = w >> 1, half = w & 1;
  __shared__ unsigned short As[4 * 536];   // shared across chains (barrier-proven)
  __shared__ float Gt2[8 * 64];
  __shared__ unsigned short GxL[512];

  // B-frags: one 16-gate-col N-tile, full K=512 -> 64 VGPR (shared by chains)
  bf16x8 breg[16];
  {
    int gcol = gi * 512 + nw * 32 + half * 16 + (lane & 15);
    const float* wrow = w_hh + (size_t)gcol * 512;
#pragma unroll
    for (int kk = 0; kk < 16; ++kk) {
      int k = kk * 32 + (lane >> 4) * 8;
      float4 f0 = *reinterpret_cast<const float4*>(wrow + k);
      float4 f1 = *reinterpret_cast<const float4*>(wrow + k + 4);
      uint4v v;
      v[0] = (unsigned)f2bf(f0.x) | ((unsigned)f2bf(f0.y) << 16);
      v[1] = (unsigned)f2bf(f0.z) | ((unsigned)f2bf(f0.w) << 16);
      v[2] = (unsigned)f2bf(f1.x) | ((unsigned)f2bf(f1.y) << 16);
      v[3] = (unsigned)f2bf(f1.z) | ((unsigned)f2bf(f1.w) << 16);
      breg[kk] = __builtin_bit_cast(bf16x8, v);
    }
  }
  // elem ownership (waves 0-1): bq=lane&3, cl=lane>>2, jl=w*16+cl
  const int bq = lane & 3;
  const int jl = (w & 1) * 16 + (lane >> 2);
  const int col = nw * 32 + jl;
  const int bnoA = bgA * 4 + bq, bnoB = bgB * 4 + bq;
  float cA = 0.0f, cB = 0.0f;
  if (w < 2) {
    cA = cx[bnoA * 512 + col];
    cB = cx[bnoB * 512 + col];
    asm volatile("" :: "v"(cA), "v"(cB));  // force materialization pre-loop
  }

  // pointers (used by waves 0-1 only)
  unsigned int* pA0 = h_tag + bgA * 2048 + tid * 4;   unsigned int* pA1 = pA0 + 16384;
  unsigned int* pB0 = h_tag + bgB * 2048 + tid * 4;   unsigned int* pB1 = pB0 + 16384;
  unsigned int* qA0 = h_tag + bgA * 2048 + bq * 512 + col;  unsigned int* qA1 = qA0 + 16384;
  unsigned int* qB0 = h_tag + bgB * 2048 + bq * 512 + col;  unsigned int* qB1 = qB0 + 16384;
  const size_t BTH = (size_t)B_ * T_ * H_;
  float* oFA = out + (size_t)bnoA * (T_ * H_) + col;
  float* oHA = oFA + BTH;  float* oGA = oHA + BTH;
  float* oFB = out + (size_t)bnoB * (T_ * H_) + col;
  float* oHB = oFB + BTH;  float* oGB = oHB + BTH;
  const unsigned short* gA = gx_ws + ((size_t)bgA * NCG + nw) * 512 + tid * 4;
  const unsigned short* gB = gx_ws + ((size_t)bgB * NCG + nw) * 512 + tid * 4;

  uint4v hA0, hA1, hA2, hA3, hB0, hB1, hB2, hB3;
  uint2v gxA, gxB;

  // ---- prologue: polls + gx for step 0 (tags seeded 0), leave vmcnt=0
  if (w < 2) {
    POLLS(hA0, hA1, hA2, hA3, pA0);
    POLLS(hB0, hB1, hB2, hB3, pB0);
    VMWAIT(0);
    SPIN(hA0, hA1, hA2, hA3, pA0, 0u);
    SPIN(hB0, hB1, hB2, hB3, pB0, 0u);
    asm volatile("global_load_dwordx2 %0, %1, off" : "=v"(gxA) : "v"(gA));
    asm volatile("global_load_dwordx2 %0, %1, off" : "=v"(gxB) : "v"(gB));
    VMWAIT(0);
  }

  for (int t = 0; t < T_; ++t) {
    // ======== slice A ========
    if (w < 2) {
      if (t) {
        VMWAIT(9);  // retires pollsA(t) (9 ops of slice-B elem issued after)
        const unsigned int* pb = (t & 1) ? pA1 : pA0;
        SPIN(hA0, hA1, hA2, hA3, pb, (unsigned)t);
      }
      UNPACK(hA0, hA1, hA2, hA3, gxA);
    }
    BARRIER_LGKM();   // As + GxL ready
    MFMA_BLOCK();
    BARRIER_LGKM();   // Gt2 ready
    if (w < 2)
      ELEM(cA, bnoA, qA0, qA1, oFA, oHA, oGA, gA, gxA, pA0, pA1, hA0, hA1, hA2, hA3);
    // ======== slice B ========
    if (w < 2) {
      if (t) {
        VMWAIT(9);  // retires pollsB(t) (9 ops of slice-A elem issued after)
        const unsigned int* pb = (t & 1) ? pB1 : pB0;
        SPIN(hB0, hB1, hB2, hB3, pb, (unsigned)t);
      }
      UNPACK(hB0, hB1, hB2, hB3, gxB);
    }
    BARRIER_LGKM();
    MFMA_BLOCK();
    BARRIER_LGKM();
    if (w < 2)
      ELEM(cB, bnoB, qB0, qB1, oFB, oHB, oGB, gB, gxB, pB0, pB1, hB0, hB1, hB2, hB3);
  }
}

extern "C" void kernel_launch(void* const* d_in, const int* in_sizes, int n_in,
                              void* d_out, int out_size, void* d_ws, size_t ws_size,
                              hipStream_t stream) {
  const float* x    = (const float*)d_in[0];
  const float* hx   = (const float*)d_in[1];
  const float* cx   = (const float*)d_in[2];
  const float* w_ih = (const float*)d_in[3];
  const float* w_hh = (const float*)d_in[4];
  const float* b_ih = (const float*)d_in[5];
  const float* b_hh = (const float*)d_in[6];
  float* out = (float*)d_out;
  char* ws = (char*)d_ws;
  const size_t OFF_XBF  = 0;                    // 67,108,864
  const size_t OFF_WBF  = 67108864;             //  2,097,152
  const size_t OFF_GX   = 69206016;             // 268,435,456
  const size_t OFF_HTAG = 337641472;            //    131,072
  const size_t NEEDED   = 337772544;
  if (ws_size < NEEDED) return;

  unsigned short* x_bf  = (unsigned short*)(ws + OFF_XBF);
  unsigned short* w_bf  = (unsigned short*)(ws + OFF_WBF);
  unsigned short* gx_ws = (unsigned short*)(ws + OFF_GX);
  unsigned int*   h_tag = (unsigned int*)(ws + OFF_HTAG);

  prep_kernel<<<16912, 256, 0, stream>>>(x, w_ih, hx, x_bf, w_bf, h_tag);
  gemm_gx<<<8192, 256, 0, stream>>>(x_bf, w_bf, b_ih, b_hh, gx_ws);
  lstm_rec<<<64, 512, 0, stream>>>(cx, w_hh, gx_ws, h_tag, out);
}